// Round 10
// baseline (76.392 us; speedup 1.0000x reference)
//
#include <hip/hip_runtime.h>
#include <hip/hip_bf16.h>

// CombinedLoss: 0.9*MSE + 0.1*margin-ranking + 0.1*(1 - mean cos), N fp32.
//
// Margin (upper-tri) = 0.5 * ordered-pair sum of relu(s*u),
//   u = yi - yj, s = (li<lj ? +1 : -1)   (exact-tie error ~0, measure-zero)
// relu(s*u) = 0.5*(|u| + s*u):
//   A += |u|                  (v_add_f32 with |src| modifier)
//   B += (li<lj ? u : -u)     (v_cmp + v_cndmask(+/-u) + v_add)
// => 5 VALU per pair; VALU floor at N=8192: 67.1M*5/64 lanes *2cyc /1024 SIMD
//    /2.4GHz ~= 4.3 us. M_PER=8 i's/thread amortizes LDS + loop overhead.
// Single fused kernel: per-block atomicAdd partials + done-counter; the last
// block to finish computes the final scalar (saves the finalize launch).

constexpr int BLOCK = 256;
constexpr int M_PER = 8;                 // i's per thread
constexpr int ITILE = BLOCK * M_PER;     // 2048 i's per i-tile
constexpr int JCH   = 64;                // j's per block

#define EPS_F 1e-8f

__global__ __launch_bounds__(BLOCK) void combined_loss_fused_kernel(
    const float* __restrict__ y, const float* __restrict__ l, int N, int JT,
    int total_blocks,
    float* __restrict__ acc,        // [3] h, mse, cos partial accumulators (zeroed)
    unsigned int* __restrict__ done, // [1] completion counter (zeroed)
    float* __restrict__ out)
{
    __shared__ float sy[JCH];
    __shared__ float sl[JCH];
    __shared__ float red[BLOCK / 64];

    const int bx  = blockIdx.x;
    const int it  = bx / JT;
    const int jt  = bx % JT;
    const int tid = threadIdx.x;

    float yi[M_PER], li[M_PER];
    bool  vm[M_PER];
#pragma unroll
    for (int m = 0; m < M_PER; ++m) {
        const int i = it * ITILE + m * BLOCK + tid;
        vm[m] = (i < N);
        yi[m] = vm[m] ? y[i] : 0.f;
        li[m] = vm[m] ? l[i] : 0.f;
    }

    const int j0   = jt * JCH;
    const int jcnt = min(JCH, N - j0);
    if (tid < JCH) {
        const bool vj = (tid < jcnt);
        sy[tid] = vj ? y[j0 + tid] : 0.f;
        sl[tid] = vj ? l[j0 + tid] : 0.f;
    }
    __syncthreads();

    float A[M_PER], B[M_PER];
#pragma unroll
    for (int m = 0; m < M_PER; ++m) { A[m] = 0.f; B[m] = 0.f; }

#define PROC(yj, lj)                                         \
    {                                                        \
        _Pragma("unroll")                                    \
        for (int m = 0; m < M_PER; ++m) {                    \
            const float u = yi[m] - (yj);                    \
            A[m] += fabsf(u);                                \
            B[m] += (li[m] < (lj)) ? u : -u;                 \
        }                                                    \
    }

    const int kv = jcnt & ~3;
    for (int k = 0; k < kv; k += 4) {
        const float4 y4 = *reinterpret_cast<const float4*>(&sy[k]);
        const float4 l4 = *reinterpret_cast<const float4*>(&sl[k]);
        PROC(y4.x, l4.x);
        PROC(y4.y, l4.y);
        PROC(y4.z, l4.z);
        PROC(y4.w, l4.w);
    }
    for (int k = kv; k < jcnt; ++k) PROC(sy[k], sl[k]);
#undef PROC

    // per-thread ordered-pair hinge sum (drop invalid i's)
    float h = 0.f;
#pragma unroll
    for (int m = 0; m < M_PER; ++m)
        if (vm[m]) h += 0.5f * (A[m] + B[m]);

    // ---- block reduce h ----
    for (int o = 32; o > 0; o >>= 1) h += __shfl_down(h, o, 64);
    const int lane = tid & 63, wid = tid >> 6;
    if (lane == 0) red[wid] = h;
    __syncthreads();
    float hblk = 0.f;
    if (tid == 0) for (int w = 0; w < BLOCK / 64; ++w) hblk += red[w];

    // ---- linear terms (MSE, cos): jt==0 blocks only ----
    float mblk = 0.f, cblk = 0.f;
    if (jt == 0) {
        float msum = 0.f, csum = 0.f;
#pragma unroll
        for (int m = 0; m < M_PER; ++m) {
            if (vm[m]) {
                const float d = yi[m] - li[m];
                msum += d * d;
                csum += (yi[m] * li[m]) /
                        (fmaxf(fabsf(yi[m]), EPS_F) * fmaxf(fabsf(li[m]), EPS_F));
            }
        }
        for (int o = 32; o > 0; o >>= 1) {
            msum += __shfl_down(msum, o, 64);
            csum += __shfl_down(csum, o, 64);
        }
        __syncthreads();
        if (lane == 0) red[wid] = msum;
        __syncthreads();
        if (tid == 0) for (int w = 0; w < BLOCK / 64; ++w) mblk += red[w];
        __syncthreads();
        if (lane == 0) red[wid] = csum;
        __syncthreads();
        if (tid == 0) for (int w = 0; w < BLOCK / 64; ++w) cblk += red[w];
    }

    // ---- commit partials; last block finalizes ----
    if (tid == 0) {
        atomicAdd(&acc[0], hblk);
        if (jt == 0) {
            atomicAdd(&acc[1], mblk);
            atomicAdd(&acc[2], cblk);
        }
        __threadfence();
        const unsigned int old = atomicAdd(done, 1u);
        if (old == (unsigned int)(total_blocks - 1)) {
            // all blocks' atomics are visible (device-scope RMW + fences)
            const double H = (double)atomicAdd(&acc[0], 0.f);
            const double M = (double)atomicAdd(&acc[1], 0.f);
            const double C = (double)atomicAdd(&acc[2], 0.f);
            const double Nd     = (double)N;
            const double mse    = M / Nd;
            const double pairs  = Nd * (Nd - 1.0) * 0.5;
            const double margin = (H * 0.5) / pairs;  // ordered/2 = upper-tri
            const double sim    = 1.0 - C / Nd;
            out[0] = (float)(0.9 * mse + 0.1 * margin + 0.1 * sim);
        }
    }
}

extern "C" void kernel_launch(void* const* d_in, const int* in_sizes, int n_in,
                              void* d_out, int out_size, void* d_ws, size_t ws_size,
                              hipStream_t stream) {
    const float* y = (const float*)d_in[0];
    const float* l = (const float*)d_in[1];
    const int N = in_sizes[0];

    const int IT = (N + ITILE - 1) / ITILE;   // 4 at N=8192
    const int JT = (N + JCH - 1) / JCH;       // 128 at N=8192
    const int total_blocks = IT * JT;         // 512 -> 2 blocks/CU, no tail

    float* acc         = (float*)d_ws;        // [3]
    unsigned int* done = (unsigned int*)(acc + 3);

    hipMemsetAsync(d_ws, 0, 4 * sizeof(float), stream);
    combined_loss_fused_kernel<<<total_blocks, BLOCK, 0, stream>>>(
        y, l, N, JT, total_blocks, acc, done, (float*)d_out);
}

// Round 12
// 68.548 us; speedup vs baseline: 1.1144x; 1.1144x over previous
//
#include <hip/hip_runtime.h>
#include <hip/hip_bf16.h>

// CombinedLoss: 0.9*MSE + 0.1*margin-ranking + 0.1*(1 - mean cos), N fp32.
//
// Margin (upper-tri) = 0.5 * ordered-pair sum of relu(s*u),
//   u = yi - yj, s = (li<lj ? +1 : -1)   (exact-tie error ~0, measure-zero)
// relu(s*u) = 0.5*(|u| + s*u):
//   A += |u|                  (v_add_f32 with |src| modifier)
//   B += (li<lj ? u : -u)     (v_cmp + v_cndmask(+/-u) + v_add)
// => 5 VALU per pair; VALU floor at N=8192 ~= 4.3 us.
// Two-kernel structure (R2, best measured 68.5us): deterministic per-block
// partials to d_ws, then a 1-block finalize. No memset, no atomics —
// R10 showed fused+memsetAsync regressed (76.4us).

constexpr int BLOCK = 256;
constexpr int M_PER = 8;                 // i's per thread
constexpr int ITILE = BLOCK * M_PER;     // 2048 i's per i-tile
constexpr int JCH   = 64;                // j's per block

#define EPS_F 1e-8f

__global__ __launch_bounds__(BLOCK) void combined_loss_pair_kernel(
    const float* __restrict__ y, const float* __restrict__ l, int N, int JT,
    float* __restrict__ hpart,   // [IT*JT] ordered-pair hinge partial per block
    float* __restrict__ mpart,   // [IT] MSE partial (jt==0 blocks)
    float* __restrict__ cpart)   // [IT] cos partial
{
    __shared__ float sy[JCH];
    __shared__ float sl[JCH];
    __shared__ float red[BLOCK / 64];

    const int bx  = blockIdx.x;
    const int it  = bx / JT;
    const int jt  = bx % JT;
    const int tid = threadIdx.x;

    float yi[M_PER], li[M_PER];
    bool  vm[M_PER];
#pragma unroll
    for (int m = 0; m < M_PER; ++m) {
        const int i = it * ITILE + m * BLOCK + tid;
        vm[m] = (i < N);
        yi[m] = vm[m] ? y[i] : 0.f;
        li[m] = vm[m] ? l[i] : 0.f;
    }

    const int j0   = jt * JCH;
    const int jcnt = min(JCH, N - j0);
    if (tid < JCH) {
        const bool vj = (tid < jcnt);
        sy[tid] = vj ? y[j0 + tid] : 0.f;
        sl[tid] = vj ? l[j0 + tid] : 0.f;
    }
    __syncthreads();

    float A[M_PER], B[M_PER];
#pragma unroll
    for (int m = 0; m < M_PER; ++m) { A[m] = 0.f; B[m] = 0.f; }

#define PROC(yj, lj)                                         \
    {                                                        \
        _Pragma("unroll")                                    \
        for (int m = 0; m < M_PER; ++m) {                    \
            const float u = yi[m] - (yj);                    \
            A[m] += fabsf(u);                                \
            B[m] += (li[m] < (lj)) ? u : -u;                 \
        }                                                    \
    }

    const int kv = jcnt & ~3;
    for (int k = 0; k < kv; k += 4) {
        const float4 y4 = *reinterpret_cast<const float4*>(&sy[k]);
        const float4 l4 = *reinterpret_cast<const float4*>(&sl[k]);
        PROC(y4.x, l4.x);
        PROC(y4.y, l4.y);
        PROC(y4.z, l4.z);
        PROC(y4.w, l4.w);
    }
    for (int k = kv; k < jcnt; ++k) PROC(sy[k], sl[k]);
#undef PROC

    // per-thread ordered-pair hinge sum (drop invalid i's)
    float h = 0.f;
#pragma unroll
    for (int m = 0; m < M_PER; ++m)
        if (vm[m]) h += 0.5f * (A[m] + B[m]);

    // ---- block reduce h ----
    for (int o = 32; o > 0; o >>= 1) h += __shfl_down(h, o, 64);
    const int lane = tid & 63, wid = tid >> 6;
    if (lane == 0) red[wid] = h;
    __syncthreads();
    if (tid == 0) {
        float s = 0.f;
        for (int w = 0; w < BLOCK / 64; ++w) s += red[w];
        hpart[bx] = s;
    }
    __syncthreads();

    // ---- linear terms (MSE, cos): jt==0 blocks only ----
    if (jt == 0) {
        float msum = 0.f, csum = 0.f;
#pragma unroll
        for (int m = 0; m < M_PER; ++m) {
            if (vm[m]) {
                const float d = yi[m] - li[m];
                msum += d * d;
                csum += (yi[m] * li[m]) /
                        (fmaxf(fabsf(yi[m]), EPS_F) * fmaxf(fabsf(li[m]), EPS_F));
            }
        }
        for (int o = 32; o > 0; o >>= 1) {
            msum += __shfl_down(msum, o, 64);
            csum += __shfl_down(csum, o, 64);
        }
        if (lane == 0) red[wid] = msum;
        __syncthreads();
        float mtot = 0.f;
        if (tid == 0) for (int w = 0; w < BLOCK / 64; ++w) mtot += red[w];
        __syncthreads();
        if (lane == 0) red[wid] = csum;
        __syncthreads();
        if (tid == 0) {
            float ctot = 0.f;
            for (int w = 0; w < BLOCK / 64; ++w) ctot += red[w];
            mpart[it] = mtot;
            cpart[it] = ctot;
        }
    }
}

__global__ __launch_bounds__(256) void combined_loss_finalize_kernel(
    const float* __restrict__ hpart, const float* __restrict__ mpart,
    const float* __restrict__ cpart, int nh, int nm, int N,
    float* __restrict__ out)
{
    double h = 0.0, m = 0.0, c = 0.0;
    for (int k = threadIdx.x; k < nh; k += blockDim.x) h += (double)hpart[k];
    for (int k = threadIdx.x; k < nm; k += blockDim.x) {
        m += (double)mpart[k];
        c += (double)cpart[k];
    }
    for (int o = 32; o > 0; o >>= 1) {
        h += __shfl_down(h, o, 64);
        m += __shfl_down(m, o, 64);
        c += __shfl_down(c, o, 64);
    }
    __shared__ double sh[4][3];
    const int lane = threadIdx.x & 63, wid = threadIdx.x >> 6;
    if (lane == 0) { sh[wid][0] = h; sh[wid][1] = m; sh[wid][2] = c; }
    __syncthreads();
    if (threadIdx.x == 0) {
        double H = 0, M = 0, C = 0;
        for (int w = 0; w < 4; ++w) { H += sh[w][0]; M += sh[w][1]; C += sh[w][2]; }
        const double Nd     = (double)N;
        const double mse    = M / Nd;
        const double pairs  = Nd * (Nd - 1.0) * 0.5;
        const double margin = (H * 0.5) / pairs;  // ordered-sum/2 = upper-tri
        const double sim    = 1.0 - C / Nd;
        out[0] = (float)(0.9 * mse + 0.1 * margin + 0.1 * sim);
    }
}

extern "C" void kernel_launch(void* const* d_in, const int* in_sizes, int n_in,
                              void* d_out, int out_size, void* d_ws, size_t ws_size,
                              hipStream_t stream) {
    const float* y = (const float*)d_in[0];
    const float* l = (const float*)d_in[1];
    const int N = in_sizes[0];

    const int IT = (N + ITILE - 1) / ITILE;   // 4 at N=8192
    const int JT = (N + JCH - 1) / JCH;       // 128 at N=8192

    float* hpart = (float*)d_ws;
    float* mpart = hpart + (size_t)IT * JT;
    float* cpart = mpart + IT;

    combined_loss_pair_kernel<<<IT * JT, BLOCK, 0, stream>>>(y, l, N, JT,
                                                             hpart, mpart, cpart);
    combined_loss_finalize_kernel<<<1, 256, 0, stream>>>(hpart, mpart, cpart,
                                                         IT * JT, IT, N,
                                                         (float*)d_out);
}